// Round 4
// baseline (217.271 us; speedup 1.0000x reference)
//
#include <hip/hip_runtime.h>
#include <hip/hip_bf16.h>
#include <math.h>

#define DEVFN __device__ __forceinline__

typedef __attribute__((ext_vector_type(8))) __bf16 bf16x8;
typedef __attribute__((ext_vector_type(8))) short s16x8;
typedef __attribute__((ext_vector_type(4))) float f32x4;
typedef __attribute__((ext_vector_type(4))) unsigned int u32x4;

constexpr int Tt    = 2048;
constexpr int INt   = 128;
constexpr int Ht    = 256;
constexpr int OUTt  = 8;
constexpr int TT    = 64;           // time tile
constexpr int NTILE = Tt / TT;      // 32

union Frag {
  s16x8 s;
  bf16x8 b;
  u32x4 u;
};

DEVFN unsigned short f2bf(float f) {
  unsigned int u = __builtin_bit_cast(unsigned int, f);
  u += 0x7fffu + ((u >> 16) & 1u);   // round-to-nearest-even
  return (unsigned short)(u >> 16);
}

DEVFN unsigned int pack2(float lo, float hi) {
  return (unsigned int)f2bf(lo) | ((unsigned int)f2bf(hi) << 16);
}

__global__ __launch_bounds__(1024, 4) void sfnn_fused(
    const float* __restrict__ x, const float* __restrict__ Wb,
    const float* __restrict__ bb, const float* __restrict__ Wo,
    const float* __restrict__ bo, const float* __restrict__ tau_m,
    const float* __restrict__ tau_n, float* __restrict__ out)
{
  const int b    = blockIdx.x;
  const int tid  = threadIdx.x;
  const int lane = tid & 63;
  const int w    = tid >> 6;          // wave id 0..15
  const int l16  = lane & 15;
  const int lhi  = lane >> 4;

  // D-GEMM wave geometry: 64t x 256h tile, each wave a 32x32 patch
  const int tg = w >> 3;              // rows [32tg, 32tg+32)
  const int hg = w & 7;               // cols [32hg, 32hg+32)
  // projection wave geometry: wave = 16t rows x 64-wide k slice
  const int tp = w >> 2;
  const int hp = w & 3;

  __shared__ __align__(16) unsigned char Xb[2][TT * INt * 2];   // bf16, swizzled
  __shared__ __align__(16) float          Df[TT * Ht];          // f32, swizzled
  __shared__ __align__(16) unsigned char  Mb[TT * Ht * 2];      // bf16, swizzled
  __shared__ float Plds[4][4][16][16];                          // [tp][hp][t16][j]

  // per-channel scan params (threads 0..255: channel = tid)
  const int   hch   = tid & 255;
  const float beta  = 1.f / (1.f + expf(-tau_n[hch]));
  const float alpha = 1.f / (1.f + expf(-tau_m[hch]));
  const float omb   = 1.f - beta;
  const float oma   = 1.f - alpha;
  const float bbh   = bb[hch];
  const float bo_j  = bo[tid & 7];

  // ---- branch-weight fragments (B operand of D-GEMM), registers all kernel ----
  Frag Wf[2][4];                      // [16-col half][k-step]
  #pragma unroll
  for (int nh = 0; nh < 2; ++nh) {
    const int h = 32 * hg + 16 * nh + l16;
    const int n = h >> 6, s = h & 63;
    #pragma unroll
    for (int ks = 0; ks < 4; ++ks) {
      #pragma unroll
      for (int j = 0; j < 8; ++j) {
        const int i = 32 * ks + 8 * lhi + j;
        Wf[nh][ks].s[j] = (short)f2bf(Wb[(n * 128 + i) * 64 + s]);
      }
    }
  }
  // ---- output-weight fragments (B operand of projection, cols >=8 zero) ----
  Frag WoF[2];
  #pragma unroll
  for (int ks = 0; ks < 2; ++ks) {
    #pragma unroll
    for (int j = 0; j < 8; ++j) {
      const int kk = 64 * hp + 32 * ks + 8 * lhi + j;
      const float v = (l16 < OUTt) ? Wo[kk * OUTt + l16] : 0.f;
      WoF[ks].s[j] = (short)f2bf(v);
    }
  }

  const float* xb   = x   + (size_t)b * Tt * INt;
  float*       outb = out + (size_t)b * Tt * OUTt;

  float c_s = 0.f, m_s = 0.f;

  // ---------------- async-pipeline primitives ----------------
  // barrier WITHOUT vmcnt drain: LDS ordering only (prefetch loads stay in flight)
  #define BAR() do {                                                       \
    asm volatile("s_waitcnt lgkmcnt(0)" ::: "memory");                     \
    __builtin_amdgcn_s_barrier();                                          \
  } while (0)

  // counted vmcnt wait (immediate) + scheduling fence (rule #18)
  #define WAITVM(N) do {                                                   \
    asm volatile("s_waitcnt vmcnt(" #N ")" ::: "memory");                  \
    __builtin_amdgcn_sched_barrier(0);                                     \
  } while (0)

  // issue: 2 coalesced 16B loads via asm volatile (compiler cannot sink them)
  #define ISSUE(TILE, Q0, Q1) do {                                         \
    const float* _p = xb + (size_t)(TILE) * (TT * INt) + 4 * (size_t)tid;  \
    asm volatile("global_load_dwordx4 %0, %1, off"                         \
                 : "=&v"(Q0) : "v"(_p));                                   \
    asm volatile("global_load_dwordx4 %0, %1, off"                         \
                 : "=&v"(Q1) : "v"(_p + 4096));                            \
  } while (0)

  // stage: pack 2 f32x4 -> 2x b64 LDS writes (swizzled); same mapping as r3
  #define STAGE(BUF, Q0, Q1) do {                                          \
    {                                                                      \
      const int R = 0 * 32 + (tid >> 5);                                   \
      const int bc = 8 * (tid & 31);                                       \
      unsigned long long pk = (unsigned long long)pack2(Q0.x, Q0.y) |      \
            ((unsigned long long)pack2(Q0.z, Q0.w) << 32);                 \
      *(unsigned long long*)(&Xb[BUF][R * 256 + (bc ^ ((R & 7) << 4))]) = pk; \
    }                                                                      \
    {                                                                      \
      const int R = 1 * 32 + (tid >> 5);                                   \
      const int bc = 8 * (tid & 31);                                       \
      unsigned long long pk = (unsigned long long)pack2(Q1.x, Q1.y) |      \
            ((unsigned long long)pack2(Q1.z, Q1.w) << 32);                 \
      *(unsigned long long*)(&Xb[BUF][R * 256 + (bc ^ ((R & 7) << 4))]) = pk; \
    }                                                                      \
  } while (0)

  #define GEMM(BUF, DACC) do {                                             \
    _Pragma("unroll")                                                      \
    for (int th = 0; th < 2; ++th) {                                       \
      const int row = 32 * tg + 16 * th + l16;                             \
      const int rs = row * 256, sw = (row & 7) << 4;                       \
      _Pragma("unroll")                                                    \
      for (int ks = 0; ks < 4; ++ks) {                                     \
        Frag a;                                                            \
        a.u = *(const u32x4*)(&Xb[BUF][rs + ((64 * ks + 16 * lhi) ^ sw)]); \
        _Pragma("unroll")                                                  \
        for (int nh = 0; nh < 2; ++nh)                                     \
          DACC[th][nh] = __builtin_amdgcn_mfma_f32_16x16x32_bf16(          \
              a.b, Wf[nh][ks].b, DACC[th][nh], 0, 0, 0);                   \
      }                                                                    \
    }                                                                      \
  } while (0)

  #define WRITEDF(DACC) do {                                               \
    _Pragma("unroll")                                                      \
    for (int th = 0; th < 2; ++th)                                         \
      _Pragma("unroll")                                                    \
      for (int nh = 0; nh < 2; ++nh) {                                     \
        const int h = 32 * hg + 16 * nh + l16;                             \
        _Pragma("unroll")                                                  \
        for (int r = 0; r < 4; ++r) {                                      \
          const int t = 32 * tg + 16 * th + 4 * lhi + r;                   \
          Df[t * 256 + (h ^ (((t >> 2) & 3) << 4))] = DACC[th][nh][r];     \
        }                                                                  \
      }                                                                    \
  } while (0)

  #define SCAN() do {                                                      \
    if (tid < 256) {                                                       \
      _Pragma("unroll")                                                    \
      for (int t = 0; t < TT; ++t) {                                       \
        const float d = Df[t * 256 + (tid ^ (((t >> 2) & 3) << 4))] + bbh; \
        c_s = fmaf(beta, c_s, omb * d);                                    \
        m_s = fmaf(alpha, m_s, oma * c_s);                                 \
        *(unsigned short*)(&Mb[(t * 256 + (tid ^ ((t & 7) << 3))) * 2]) = f2bf(m_s); \
      }                                                                    \
    }                                                                      \
  } while (0)

  #define PROJ() do {                                                      \
    f32x4 p = f32x4{0.f, 0.f, 0.f, 0.f};                                   \
    const int trow = 16 * tp + l16;                                        \
    _Pragma("unroll")                                                      \
    for (int ks = 0; ks < 2; ++ks) {                                       \
      const int h0 = 64 * hp + 32 * ks + 8 * lhi;                          \
      Frag ma;                                                             \
      ma.u = *(const u32x4*)(&Mb[(trow * 256 + (h0 ^ ((trow & 7) << 3))) * 2]); \
      p = __builtin_amdgcn_mfma_f32_16x16x32_bf16(ma.b, WoF[ks].b, p, 0, 0, 0); \
    }                                                                      \
    _Pragma("unroll")                                                      \
    for (int r = 0; r < 4; ++r)                                            \
      Plds[tp][hp][4 * lhi + r][l16] = p[r];                               \
  } while (0)

  #define STORE(I) do {                                                    \
    if (tid < 512) {                                                       \
      const int trow = tid >> 3, j = tid & 7;                              \
      const int t16 = trow & 15, ts = trow >> 4;                           \
      const float sum = Plds[ts][0][t16][j] + Plds[ts][1][t16][j] +        \
                        Plds[ts][2][t16][j] + Plds[ts][3][t16][j] + bo_j;  \
      outb[(size_t)((I) * TT + trow) * OUTt + j] = 1.f / (1.f + __expf(-sum)); \
    }                                                                      \
  } while (0)

  // ---------------- prologue ----------------
  f32x4 PA0, PA1, PB0, PB1;
  ISSUE(0, PA0, PA1);                 // loads(0) in flight
  ISSUE(1, PB0, PB1);                 // loads(1) in flight
  WAITVM(2);                          // wait loads(0), keep loads(1)
  STAGE(0, PA0, PA1);                 // tile 0 -> Xb[0]
  WAITVM(0);                          // wait loads(1)
  STAGE(1, PB0, PB1);                 // tile 1 -> Xb[1]
  ISSUE(2, PA0, PA1);                 // loads(2) in flight across barrier
  BAR();
  {
    f32x4 d0[2][2];
    #pragma unroll
    for (int th = 0; th < 2; ++th)
      #pragma unroll
      for (int nh = 0; nh < 2; ++nh) d0[th][nh] = f32x4{0.f, 0.f, 0.f, 0.f};
    GEMM(0, d0);                      // tile 0
    WRITEDF(d0);
  }
  BAR();

  // ---------------- iteration body ----------------
  // Per iter I: compute GEMM(I+1) + scan(I) | B1 | writeDf(I+1), wait+stage(I+2),
  // proj(I) | B2 | store(I).  Loads for tile I+3 issued at top, in flight the
  // whole iteration (vmcnt(2) leaves them pending).
  #define ITER(I, PW0, PW1, PI0, PI1, DOISS, DOSTG, DOGEMM, WN) do {       \
    if (DOISS) ISSUE((I) + 3, PI0, PI1);                                   \
    f32x4 dacc[2][2];                                                      \
    _Pragma("unroll")                                                      \
    for (int th = 0; th < 2; ++th)                                         \
      _Pragma("unroll")                                                    \
      for (int nh = 0; nh < 2; ++nh) dacc[th][nh] = f32x4{0.f,0.f,0.f,0.f};\
    if (DOGEMM) GEMM(((I) + 1) & 1, dacc);                                 \
    SCAN();                                                                \
    BAR();            /* B1 */                                             \
    if (DOGEMM) WRITEDF(dacc);                                             \
    if (DOSTG) { WAITVM(WN); STAGE((I) & 1, PW0, PW1); }                   \
    PROJ();                                                                \
    BAR();            /* B2 */                                             \
    STORE(I);                                                              \
  } while (0)

  // main loop: I = 0..27, full pipeline (all flags true, wait vmcnt(2))
  for (int ii = 0; ii < 14; ++ii) {
    ITER(2 * ii,     PA0, PA1, PB0, PB1, 1, 1, 1, 2);
    ITER(2 * ii + 1, PB0, PB1, PA0, PA1, 1, 1, 1, 2);
  }
  // epilogue: static flags / wait immediates
  ITER(28, PA0, PA1, PB0, PB1, 1, 1, 1, 2);  // issues loads(31), stages tile 30
  ITER(29, PB0, PB1, PA0, PA1, 0, 1, 1, 0);  // stages tile 31 (drain)
  ITER(30, PA0, PA1, PB0, PB1, 0, 0, 1, 0);  // GEMM(31), scan(30)
  ITER(31, PB0, PB1, PA0, PA1, 0, 0, 0, 0);  // scan(31), proj, store

  #undef ISSUE
  #undef STAGE
  #undef GEMM
  #undef WRITEDF
  #undef SCAN
  #undef PROJ
  #undef STORE
  #undef ITER
  #undef BAR
  #undef WAITVM
}

extern "C" void kernel_launch(void* const* d_in, const int* in_sizes, int n_in,
                              void* d_out, int out_size, void* d_ws, size_t ws_size,
                              hipStream_t stream) {
  const float* x     = (const float*)d_in[0];
  const float* Wb    = (const float*)d_in[1];
  const float* bb    = (const float*)d_in[2];
  const float* Wo    = (const float*)d_in[3];
  const float* bo    = (const float*)d_in[4];
  const float* tau_m = (const float*)d_in[5];
  const float* tau_n = (const float*)d_in[6];
  float* out = (float*)d_out;

  sfnn_fused<<<dim3(256), dim3(1024), 0, stream>>>(x, Wb, bb, Wo, bo, tau_m, tau_n, out);
}

// Round 5
// 217.155 us; speedup vs baseline: 1.0005x; 1.0005x over previous
//
#include <hip/hip_runtime.h>
#include <hip/hip_bf16.h>
#include <math.h>

#define DEVFN __device__ __forceinline__

typedef __attribute__((ext_vector_type(8))) __bf16 bf16x8;
typedef __attribute__((ext_vector_type(8))) short s16x8;
typedef __attribute__((ext_vector_type(4))) float f32x4;
typedef __attribute__((ext_vector_type(4))) unsigned int u32x4;

constexpr int Tt    = 2048;
constexpr int INt   = 128;
constexpr int Ht    = 256;
constexpr int OUTt  = 8;
constexpr int TT    = 64;           // time tile
constexpr int NTILE = Tt / TT;      // 32

union Frag {
  s16x8 s;
  bf16x8 b;
  u32x4 u;
};

DEVFN unsigned short f2bf(float f) {
  unsigned int u = __builtin_bit_cast(unsigned int, f);
  u += 0x7fffu + ((u >> 16) & 1u);   // round-to-nearest-even
  return (unsigned short)(u >> 16);
}

DEVFN unsigned int pack2(float lo, float hi) {
  return (unsigned int)f2bf(lo) | ((unsigned int)f2bf(hi) << 16);
}

// 1024 threads = 16 waves = 4 waves/SIMD (single block/CU, LDS-limited).
// Pin waves-per-EU to exactly 4 -> 128-VGPR budget; launch_bounds(1024,4)
// let the scheduler target 8/EU (64 VGPRs) and spill the prefetch regs.
__global__
__attribute__((amdgpu_flat_work_group_size(1024, 1024), amdgpu_waves_per_eu(4, 4)))
void sfnn_fused(
    const float* __restrict__ x, const float* __restrict__ Wb,
    const float* __restrict__ bb, const float* __restrict__ Wo,
    const float* __restrict__ bo, const float* __restrict__ tau_m,
    const float* __restrict__ tau_n, float* __restrict__ out)
{
  const int b    = blockIdx.x;
  const int tid  = threadIdx.x;
  const int lane = tid & 63;
  const int w    = tid >> 6;          // wave id 0..15
  const int l16  = lane & 15;
  const int lhi  = lane >> 4;

  // D-GEMM wave geometry: 64t x 256h tile, each wave a 32x32 patch
  const int tg = w >> 3;              // rows [32tg, 32tg+32)
  const int hg = w & 7;               // cols [32hg, 32hg+32)
  // projection wave geometry: wave = 16t rows x 64-wide k slice
  const int tp = w >> 2;
  const int hp = w & 3;

  __shared__ __align__(16) unsigned char Xb[2][TT * INt * 2];   // bf16, swizzled
  __shared__ __align__(16) float          Df[TT * Ht];          // f32, swizzled
  __shared__ __align__(16) unsigned char  Mb[TT * Ht * 2];      // bf16, swizzled
  __shared__ float Plds[4][4][16][16];                          // [tp][hp][t16][j]

  // per-channel scan params (threads 0..255: channel = tid)
  const int   hch   = tid & 255;
  const float beta  = 1.f / (1.f + expf(-tau_n[hch]));
  const float alpha = 1.f / (1.f + expf(-tau_m[hch]));
  const float omb   = 1.f - beta;
  const float oma   = 1.f - alpha;
  const float bbh   = bb[hch];
  const float bo_j  = bo[tid & 7];

  // ---- branch-weight fragments (B operand of D-GEMM), registers all kernel ----
  Frag Wf[2][4];                      // [16-col half][k-step]
  #pragma unroll
  for (int nh = 0; nh < 2; ++nh) {
    const int h = 32 * hg + 16 * nh + l16;
    const int n = h >> 6, s = h & 63;
    #pragma unroll
    for (int ks = 0; ks < 4; ++ks) {
      #pragma unroll
      for (int j = 0; j < 8; ++j) {
        const int i = 32 * ks + 8 * lhi + j;
        Wf[nh][ks].s[j] = (short)f2bf(Wb[(n * 128 + i) * 64 + s]);
      }
    }
  }
  // ---- output-weight fragments (B operand of projection, cols >=8 zero) ----
  Frag WoF[2];
  #pragma unroll
  for (int ks = 0; ks < 2; ++ks) {
    #pragma unroll
    for (int j = 0; j < 8; ++j) {
      const int kk = 64 * hp + 32 * ks + 8 * lhi + j;
      const float v = (l16 < OUTt) ? Wo[kk * OUTt + l16] : 0.f;
      WoF[ks].s[j] = (short)f2bf(v);
    }
  }

  const float* xb   = x   + (size_t)b * Tt * INt;
  float*       outb = out + (size_t)b * Tt * OUTt;

  float c_s = 0.f, m_s = 0.f;

  // ---------------- async-pipeline primitives ----------------
  // barrier WITHOUT vmcnt drain: LDS ordering only (prefetch loads stay in flight)
  #define BAR() do {                                                       \
    asm volatile("s_waitcnt lgkmcnt(0)" ::: "memory");                     \
    __builtin_amdgcn_s_barrier();                                          \
  } while (0)

  // counted vmcnt wait (immediate) + scheduling fence (rule #18)
  #define WAITVM(N) do {                                                   \
    asm volatile("s_waitcnt vmcnt(" #N ")" ::: "memory");                  \
    __builtin_amdgcn_sched_barrier(0);                                     \
  } while (0)

  // issue: 2 coalesced 16B loads via asm volatile (compiler cannot sink them)
  #define ISSUE(TILE, Q0, Q1) do {                                         \
    const float* _p = xb + (size_t)(TILE) * (TT * INt) + 4 * (size_t)tid;  \
    asm volatile("global_load_dwordx4 %0, %1, off"                         \
                 : "=&v"(Q0) : "v"(_p));                                   \
    asm volatile("global_load_dwordx4 %0, %1, off"                         \
                 : "=&v"(Q1) : "v"(_p + 4096));                            \
  } while (0)

  // stage: pack 2 f32x4 -> 2x b64 LDS writes (swizzled)
  #define STAGE(BUF, Q0, Q1) do {                                          \
    {                                                                      \
      const int R = 0 * 32 + (tid >> 5);                                   \
      const int bc = 8 * (tid & 31);                                       \
      unsigned long long pk = (unsigned long long)pack2(Q0.x, Q0.y) |      \
            ((unsigned long long)pack2(Q0.z, Q0.w) << 32);                 \
      *(unsigned long long*)(&Xb[BUF][R * 256 + (bc ^ ((R & 7) << 4))]) = pk; \
    }                                                                      \
    {                                                                      \
      const int R = 1 * 32 + (tid >> 5);                                   \
      const int bc = 8 * (tid & 31);                                       \
      unsigned long long pk = (unsigned long long)pack2(Q1.x, Q1.y) |      \
            ((unsigned long long)pack2(Q1.z, Q1.w) << 32);                 \
      *(unsigned long long*)(&Xb[BUF][R * 256 + (bc ^ ((R & 7) << 4))]) = pk; \
    }                                                                      \
  } while (0)

  #define GEMM(BUF, DACC) do {                                             \
    _Pragma("unroll")                                                      \
    for (int th = 0; th < 2; ++th) {                                       \
      const int row = 32 * tg + 16 * th + l16;                             \
      const int rs = row * 256, sw = (row & 7) << 4;                       \
      _Pragma("unroll")                                                    \
      for (int ks = 0; ks < 4; ++ks) {                                     \
        Frag a;                                                            \
        a.u = *(const u32x4*)(&Xb[BUF][rs + ((64 * ks + 16 * lhi) ^ sw)]); \
        _Pragma("unroll")                                                  \
        for (int nh = 0; nh < 2; ++nh)                                     \
          DACC[th][nh] = __builtin_amdgcn_mfma_f32_16x16x32_bf16(          \
              a.b, Wf[nh][ks].b, DACC[th][nh], 0, 0, 0);                   \
      }                                                                    \
    }                                                                      \
  } while (0)

  #define WRITEDF(DACC) do {                                               \
    _Pragma("unroll")                                                      \
    for (int th = 0; th < 2; ++th)                                         \
      _Pragma("unroll")                                                    \
      for (int nh = 0; nh < 2; ++nh) {                                     \
        const int h = 32 * hg + 16 * nh + l16;                             \
        _Pragma("unroll")                                                  \
        for (int r = 0; r < 4; ++r) {                                      \
          const int t = 32 * tg + 16 * th + 4 * lhi + r;                   \
          Df[t * 256 + (h ^ (((t >> 2) & 3) << 4))] = DACC[th][nh][r];     \
        }                                                                  \
      }                                                                    \
  } while (0)

  #define SCAN() do {                                                      \
    if (tid < 256) {                                                       \
      _Pragma("unroll")                                                    \
      for (int t = 0; t < TT; ++t) {                                       \
        const float d = Df[t * 256 + (tid ^ (((t >> 2) & 3) << 4))] + bbh; \
        c_s = fmaf(beta, c_s, omb * d);                                    \
        m_s = fmaf(alpha, m_s, oma * c_s);                                 \
        *(unsigned short*)(&Mb[(t * 256 + (tid ^ ((t & 7) << 3))) * 2]) = f2bf(m_s); \
      }                                                                    \
    }                                                                      \
  } while (0)

  #define PROJ() do {                                                      \
    f32x4 p = f32x4{0.f, 0.f, 0.f, 0.f};                                   \
    const int trow = 16 * tp + l16;                                        \
    _Pragma("unroll")                                                      \
    for (int ks = 0; ks < 2; ++ks) {                                       \
      const int h0 = 64 * hp + 32 * ks + 8 * lhi;                          \
      Frag ma;                                                             \
      ma.u = *(const u32x4*)(&Mb[(trow * 256 + (h0 ^ ((trow & 7) << 3))) * 2]); \
      p = __builtin_amdgcn_mfma_f32_16x16x32_bf16(ma.b, WoF[ks].b, p, 0, 0, 0); \
    }                                                                      \
    _Pragma("unroll")                                                      \
    for (int r = 0; r < 4; ++r)                                            \
      Plds[tp][hp][4 * lhi + r][l16] = p[r];                               \
  } while (0)

  #define STORE(I) do {                                                    \
    if (tid < 512) {                                                       \
      const int trow = tid >> 3, j = tid & 7;                              \
      const int t16 = trow & 15, ts = trow >> 4;                           \
      const float sum = Plds[ts][0][t16][j] + Plds[ts][1][t16][j] +        \
                        Plds[ts][2][t16][j] + Plds[ts][3][t16][j] + bo_j;  \
      outb[(size_t)((I) * TT + trow) * OUTt + j] = 1.f / (1.f + __expf(-sum)); \
    }                                                                      \
  } while (0)

  // ---------------- prologue ----------------
  f32x4 PA0, PA1, PB0, PB1;
  ISSUE(0, PA0, PA1);                 // loads(0) in flight
  ISSUE(1, PB0, PB1);                 // loads(1) in flight
  WAITVM(2);                          // wait loads(0), keep loads(1)
  STAGE(0, PA0, PA1);                 // tile 0 -> Xb[0]
  WAITVM(0);                          // wait loads(1)
  STAGE(1, PB0, PB1);                 // tile 1 -> Xb[1]
  ISSUE(2, PA0, PA1);                 // loads(2) in flight across barrier
  BAR();
  {
    f32x4 d0[2][2];
    #pragma unroll
    for (int th = 0; th < 2; ++th)
      #pragma unroll
      for (int nh = 0; nh < 2; ++nh) d0[th][nh] = f32x4{0.f, 0.f, 0.f, 0.f};
    GEMM(0, d0);                      // tile 0
    WRITEDF(d0);
  }
  BAR();

  // ---------------- iteration body ----------------
  // Per iter I: compute GEMM(I+1) + scan(I) | B1 | writeDf(I+1), wait+stage(I+2),
  // proj(I) | B2 | store(I).  Loads for tile I+3 issued at top, in flight the
  // whole iteration (vmcnt(2) leaves them pending).
  #define ITER(I, PW0, PW1, PI0, PI1, DOISS, DOSTG, DOGEMM, WN) do {       \
    if (DOISS) ISSUE((I) + 3, PI0, PI1);                                   \
    f32x4 dacc[2][2];                                                      \
    _Pragma("unroll")                                                      \
    for (int th = 0; th < 2; ++th)                                         \
      _Pragma("unroll")                                                    \
      for (int nh = 0; nh < 2; ++nh) dacc[th][nh] = f32x4{0.f,0.f,0.f,0.f};\
    if (DOGEMM) GEMM(((I) + 1) & 1, dacc);                                 \
    SCAN();                                                                \
    BAR();            /* B1 */                                             \
    if (DOGEMM) WRITEDF(dacc);                                             \
    if (DOSTG) { WAITVM(WN); STAGE((I) & 1, PW0, PW1); }                   \
    PROJ();                                                                \
    BAR();            /* B2 */                                             \
    STORE(I);                                                              \
  } while (0)

  // main loop: I = 0..27, full pipeline (all flags true, wait vmcnt(2))
  for (int ii = 0; ii < 14; ++ii) {
    ITER(2 * ii,     PA0, PA1, PB0, PB1, 1, 1, 1, 2);
    ITER(2 * ii + 1, PB0, PB1, PA0, PA1, 1, 1, 1, 2);
  }
  // epilogue: static flags / wait immediates
  ITER(28, PA0, PA1, PB0, PB1, 1, 1, 1, 2);  // issues loads(31), stages tile 30
  ITER(29, PB0, PB1, PA0, PA1, 0, 1, 1, 0);  // stages tile 31 (drain)
  ITER(30, PA0, PA1, PB0, PB1, 0, 0, 1, 0);  // GEMM(31), scan(30)
  ITER(31, PB0, PB1, PA0, PA1, 0, 0, 0, 0);  // scan(31), proj, store

  #undef ISSUE
  #undef STAGE
  #undef GEMM
  #undef WRITEDF
  #undef SCAN
  #undef PROJ
  #undef STORE
  #undef ITER
  #undef BAR
  #undef WAITVM
}

extern "C" void kernel_launch(void* const* d_in, const int* in_sizes, int n_in,
                              void* d_out, int out_size, void* d_ws, size_t ws_size,
                              hipStream_t stream) {
  const float* x     = (const float*)d_in[0];
  const float* Wb    = (const float*)d_in[1];
  const float* bb    = (const float*)d_in[2];
  const float* Wo    = (const float*)d_in[3];
  const float* bo    = (const float*)d_in[4];
  const float* tau_m = (const float*)d_in[5];
  const float* tau_n = (const float*)d_in[6];
  float* out = (float*)d_out;

  sfnn_fused<<<dim3(256), dim3(1024), 0, stream>>>(x, Wb, bb, Wo, bo, tau_m, tau_n, out);
}

// Round 6
// 106.386 us; speedup vs baseline: 2.0423x; 2.0412x over previous
//
#include <hip/hip_runtime.h>
#include <hip/hip_bf16.h>
#include <math.h>

#define DEVFN __device__ __forceinline__

typedef __attribute__((ext_vector_type(8))) __bf16 bf16x8;
typedef __attribute__((ext_vector_type(8))) short s16x8;
typedef __attribute__((ext_vector_type(4))) float f32x4;
typedef __attribute__((ext_vector_type(4))) unsigned int u32x4;

constexpr int Tt    = 2048;
constexpr int INt   = 128;
constexpr int Ht    = 256;
constexpr int OUTt  = 8;
constexpr int TT    = 64;           // time tile
constexpr int NTILE = Tt / TT;      // 32

union Frag {
  s16x8 s;
  bf16x8 b;
  u32x4 u;
};

DEVFN unsigned short f2bf(float f) {
  unsigned int u = __builtin_bit_cast(unsigned int, f);
  u += 0x7fffu + ((u >> 16) & 1u);   // round-to-nearest-even
  return (unsigned short)(u >> 16);
}

DEVFN unsigned int pack2(float lo, float hi) {
  return (unsigned int)f2bf(lo) | ((unsigned int)f2bf(hi) << 16);
}

__global__
__attribute__((amdgpu_flat_work_group_size(1024, 1024), amdgpu_waves_per_eu(4, 4)))
void sfnn_fused(
    const float* __restrict__ x, const float* __restrict__ Wb,
    const float* __restrict__ bb, const float* __restrict__ Wo,
    const float* __restrict__ bo, const float* __restrict__ tau_m,
    const float* __restrict__ tau_n, float* __restrict__ out)
{
  const int b    = blockIdx.x;
  const int tid  = threadIdx.x;
  const int lane = tid & 63;
  const int w    = tid >> 6;          // wave id 0..15
  const int l16  = lane & 15;
  const int lhi  = lane >> 4;
  const int sid  = tid - 512;         // stager index (waves 8-15)

  // LDS: 32KB Xb + 64KB DfT + 32KB Mb + 8KB WoT = 136KB
  __shared__ __align__(16) unsigned char  Xb[2][TT * 256];      // bf16 x, swizzled
  __shared__ __align__(16) float          DfT[Ht * TT];         // D transposed [h][t]
  __shared__ __align__(16) unsigned short Mb[TT * Ht];          // m bf16 [t][h]
  __shared__ __align__(16) unsigned short WoT[16 * Ht];         // Wo^T bf16 [j][k]

  // scan params (threads 0..255: channel = tid)
  const int   hch   = tid & 255;
  const float beta  = 1.f / (1.f + expf(-tau_n[hch]));
  const float alpha = 1.f / (1.f + expf(-tau_m[hch]));
  const float omb   = 1.f - beta;
  const float oma   = 1.f - alpha;
  const float bbh   = bb[hch];
  const float bo_l  = (l16 < OUTt) ? bo[l16] : 0.f;

  // ---- stage WoT: [j][k] bf16, rows j>=8 zero; thread covers 4 halves ----
  {
    const int j  = w;                  // tid*4 >> 8
    const int k0 = 4 * (tid & 63);
    float v0 = 0.f, v1 = 0.f, v2 = 0.f, v3 = 0.f;
    if (j < OUTt) {
      v0 = Wo[(k0 + 0) * OUTt + j]; v1 = Wo[(k0 + 1) * OUTt + j];
      v2 = Wo[(k0 + 2) * OUTt + j]; v3 = Wo[(k0 + 3) * OUTt + j];
    }
    unsigned long long pk = (unsigned long long)pack2(v0, v1) |
                            ((unsigned long long)pack2(v2, v3) << 32);
    *(unsigned long long*)(&WoT[j * 256 + (k0 ^ ((j & 7) << 3))]) = pk;
  }

  // ---- branch-weight fragments: wave w owns h-cols [16w, 16w+16), K=128 ----
  Frag Wf[4];                          // [k-step], 16 VGPRs
  {
    const int h = 16 * w + l16;
    const int n = h >> 6, s = h & 63;
    #pragma unroll
    for (int ks = 0; ks < 4; ++ks) {
      #pragma unroll
      for (int j = 0; j < 8; ++j) {
        const int i = 32 * ks + 8 * lhi + j;
        Wf[ks].s[j] = (short)f2bf(Wb[(n * 128 + i) * 64 + s]);
      }
    }
  }

  const float* xb   = x   + (size_t)b * Tt * INt;
  float*       outb = out + (size_t)b * Tt * OUTt;

  float c_s = 0.f, m_s = 0.f;
  f32x4 Q0, Q1, Q2, Q3;                // stager prefetch (waves 8-15 only)
  f32x4 dacc[4];                       // D accumulators (t-tiles), live across barriers

  #define BAR() do {                                                       \
    asm volatile("s_waitcnt lgkmcnt(0)" ::: "memory");                     \
    __builtin_amdgcn_s_barrier();                                          \
  } while (0)

  #define WAITVM0() do {                                                   \
    asm volatile("s_waitcnt vmcnt(0)" ::: "memory");                       \
    __builtin_amdgcn_sched_barrier(0);                                     \
  } while (0)

  // stager waves: 4 coalesced un-sinkable 16B loads (tile = 512thr*16 floats)
  #define ISSUE(TILE) do {                                                 \
    const float* _p = xb + (size_t)(TILE) * (TT * INt) + 4 * (size_t)sid;  \
    asm volatile("global_load_dwordx4 %0, %1, off" : "=&v"(Q0) : "v"(_p));         \
    asm volatile("global_load_dwordx4 %0, %1, off" : "=&v"(Q1) : "v"(_p + 2048));  \
    asm volatile("global_load_dwordx4 %0, %1, off" : "=&v"(Q2) : "v"(_p + 4096));  \
    asm volatile("global_load_dwordx4 %0, %1, off" : "=&v"(Q3) : "v"(_p + 6144));  \
  } while (0)

  // pack f32->bf16, swizzled b64 writes; float f = q*2048 + sid*4 + e
  #define STAGE(BUF) do {                                                  \
    WAITVM0();                                                             \
    const int kb = 8 * (sid & 31);                                         \
    const int tb = sid >> 5;                                               \
    f32x4 qq[4] = {Q0, Q1, Q2, Q3};                                        \
    _Pragma("unroll")                                                      \
    for (int q = 0; q < 4; ++q) {                                          \
      const int t = 16 * q + tb;                                           \
      unsigned long long pk = (unsigned long long)pack2(qq[q][0], qq[q][1]) |  \
            ((unsigned long long)pack2(qq[q][2], qq[q][3]) << 32);         \
      *(unsigned long long*)(&Xb[BUF][t * 256 + (kb ^ ((t & 7) << 4))]) = pk;  \
    }                                                                      \
  } while (0)

  // wave w: D[t=0..64)[h=16w..16w+16), K=128 -> dacc[tt] (t = 16tt+4lhi+r)
  #define GEMM(BUF) do {                                                   \
    _Pragma("unroll")                                                      \
    for (int tt = 0; tt < 4; ++tt) {                                       \
      dacc[tt] = f32x4{0.f, 0.f, 0.f, 0.f};                                \
      const int row = 16 * tt + l16;                                       \
      const int rs = row * 256, sw = (row & 7) << 4;                       \
      _Pragma("unroll")                                                    \
      for (int ks = 0; ks < 4; ++ks) {                                     \
        Frag a;                                                            \
        a.u = *(const u32x4*)(&Xb[BUF][rs + ((64 * ks + 16 * lhi) ^ sw)]); \
        dacc[tt] = __builtin_amdgcn_mfma_f32_16x16x32_bf16(                \
            a.b, Wf[ks].b, dacc[tt], 0, 0, 0);                             \
      }                                                                    \
    }                                                                      \
  } while (0)

  // write dacc -> DfT[h][t'] as b128 (4 consecutive t), t' = t ^ ((h&7)<<2)
  #define WRITEDF() do {                                                   \
    const int h = 16 * w + l16;                                            \
    const int hb = h * 64, dsw = (h & 7) << 2;                             \
    _Pragma("unroll")                                                      \
    for (int tt = 0; tt < 4; ++tt)                                         \
      *(f32x4*)(&DfT[hb + ((16 * tt + 4 * lhi) ^ dsw)]) = dacc[tt];        \
  } while (0)

  // threads 0..255: batched b128 row reads + serial EMA + Mb writes
  #define SCAN() do {                                                      \
    if (tid < 256) {                                                       \
      const int hb = tid * 64, dsw = (tid & 7) << 2;                       \
      _Pragma("unroll")                                                    \
      for (int g = 0; g < 4; ++g) {                                        \
        f32x4 dv[4];                                                       \
        _Pragma("unroll")                                                  \
        for (int q = 0; q < 4; ++q)                                        \
          dv[q] = *(const f32x4*)(&DfT[hb + ((16 * g + 4 * q) ^ dsw)]);    \
        _Pragma("unroll")                                                  \
        for (int q = 0; q < 4; ++q)                                        \
          _Pragma("unroll")                                                \
          for (int r = 0; r < 4; ++r) {                                    \
            const int t = 16 * g + 4 * q + r;                              \
            const float d = dv[q][r] + bbh;                                \
            c_s = fmaf(beta, c_s, omb * d);                                \
            m_s = fmaf(alpha, m_s, oma * c_s);                             \
            Mb[t * 256 + (tid ^ ((t & 7) << 3))] = f2bf(m_s);              \
          }                                                                \
      }                                                                    \
    }                                                                      \
  } while (0)

  // waves 4-7: rows [16tp,16tp+16), full K=256, sigmoid + store (tile TI)
  #define PROJ(TI) do {                                                    \
    const int tp = w - 4;                                                  \
    const int trow = 16 * tp + l16;                                        \
    const int mrb = trow * 256, msw = (trow & 7) << 3;                     \
    const int wrb = l16 * 256,  wsw = (l16 & 7) << 3;                      \
    f32x4 p = f32x4{0.f, 0.f, 0.f, 0.f};                                   \
    _Pragma("unroll")                                                      \
    for (int ks = 0; ks < 8; ++ks) {                                       \
      const int k0 = 32 * ks + 8 * lhi;                                    \
      Frag ma, wo;                                                         \
      ma.u = *(const u32x4*)(&Mb[mrb + (k0 ^ msw)]);                       \
      wo.u = *(const u32x4*)(&WoT[wrb + (k0 ^ wsw)]);                      \
      p = __builtin_amdgcn_mfma_f32_16x16x32_bf16(ma.b, wo.b, p, 0, 0, 0); \
    }                                                                      \
    if (l16 < OUTt) {                                                      \
      _Pragma("unroll")                                                    \
      for (int r = 0; r < 4; ++r) {                                        \
        const int t = 16 * tp + 4 * lhi + r;                               \
        outb[(size_t)((TI) * TT + t) * OUTt + l16] =                       \
            1.f / (1.f + __expf(-(p[r] + bo_l)));                          \
      }                                                                    \
    }                                                                      \
  } while (0)

  // ---------------- prologue: stage tiles 0,1; GEMM(0) ----------------
  if (w >= 8) {
    ISSUE(0); STAGE(0);
    ISSUE(1); STAGE(1);
  }
  BAR();
  GEMM(0);                             // dacc = D(0)

  // ---------------- pipeline ----------------
  // iter I: A{issue(I+2), writeDfT(I), proj(I-1), GEMM(I+1)->dacc} B1
  //         B{scan(I), stage(I+2)} B2
  #define ITER(I, DOPROJ, DOGEMM, DOIS) do {                               \
    if (DOIS && w >= 8) ISSUE((I) + 2);                                    \
    WRITEDF();                                                             \
    if (DOPROJ && w >= 4 && w < 8) PROJ((I) - 1);                          \
    if (DOGEMM) GEMM(((I) + 1) & 1);                                       \
    BAR();            /* B1 */                                             \
    SCAN();                                                                \
    if (DOIS && w >= 8) STAGE((I) & 1);                                    \
    BAR();            /* B2 */                                             \
  } while (0)

  ITER(0, 0, 1, 1);
  for (int I = 1; I <= 29; ++I) ITER(I, 1, 1, 1);
  ITER(30, 1, 1, 0);
  ITER(31, 1, 0, 0);
  if (w >= 4 && w < 8) PROJ(31);

  #undef ISSUE
  #undef STAGE
  #undef GEMM
  #undef WRITEDF
  #undef SCAN
  #undef PROJ
  #undef ITER
  #undef BAR
  #undef WAITVM0
}

extern "C" void kernel_launch(void* const* d_in, const int* in_sizes, int n_in,
                              void* d_out, int out_size, void* d_ws, size_t ws_size,
                              hipStream_t stream) {
  const float* x     = (const float*)d_in[0];
  const float* Wb    = (const float*)d_in[1];
  const float* bb    = (const float*)d_in[2];
  const float* Wo    = (const float*)d_in[3];
  const float* bo    = (const float*)d_in[4];
  const float* tau_m = (const float*)d_in[5];
  const float* tau_n = (const float*)d_in[6];
  float* out = (float*)d_out;

  sfnn_fused<<<dim3(256), dim3(1024), 0, stream>>>(x, Wb, bb, Wo, bo, tau_m, tau_n, out);
}